// Round 2
// baseline (708.222 us; speedup 1.0000x reference)
//
#include <hip/hip_runtime.h>
#include <hip/hip_bf16.h>

#define N_NODES 8192
#define DIM 64
#define VIS 2048
#define KIN 32
#define VOC 256

typedef unsigned short u16;
typedef unsigned int u32;

__device__ __forceinline__ float bflo(u32 w) {
    union { u32 i; float f; } c; c.i = w << 16; return c.f;
}
__device__ __forceinline__ float bfhi(u32 w) {
    union { u32 i; float f; } c; c.i = w & 0xffff0000u; return c.f;
}
// pack two fp32 -> two bf16 (RNE), low word = a
__device__ __forceinline__ u32 pk_bf16(float a, float b) {
    __hip_bfloat162 h = __float22bfloat162_rn(make_float2(a, b));
    u32 u; __builtin_memcpy(&u, &h, 4); return u;
}

// ---------------- Kernel 1: gather + mean over K, partial global stats ----
__global__ __launch_bounds__(256) void k_gather(
    const float* __restrict__ x, const float* __restrict__ memes,
    const int* __restrict__ idx, float* __restrict__ graw,
    float* __restrict__ part)
{
    int tid  = threadIdx.x;
    int wid  = tid >> 6;
    int lane = tid & 63;
    int n = blockIdx.x * 4 + wid;           // one wave per node
    const int* irow = idx + n * KIN;

    float acc = 0.f;
#pragma unroll
    for (int k = 0; k < KIN; ++k) {
        int id = irow[k];                   // wave-uniform load
        const float* row = (id < VIS) ? (x + (size_t)id * DIM)
                                      : (memes + (size_t)(id - VIS) * DIM);
        acc += row[lane];                   // 256B contiguous per wave
    }
    float g = acc * (1.0f / KIN);
    graw[(size_t)n * DIM + lane] = g;

    float s = g, q = g * g;
#pragma unroll
    for (int m = 32; m >= 1; m >>= 1) {
        s += __shfl_xor(s, m, 64);
        q += __shfl_xor(q, m, 64);
    }
    __shared__ float sh[8];
    if (lane == 0) { sh[wid] = s; sh[wid + 4] = q; }
    __syncthreads();
    if (tid == 0) {
        part[blockIdx.x * 2 + 0] = sh[0] + sh[1] + sh[2] + sh[3];
        part[blockIdx.x * 2 + 1] = sh[4] + sh[5] + sh[6] + sh[7];
    }
}

// ---------------- Kernel 2: finish global mean / inv-std (ddof=1) ---------
__global__ __launch_bounds__(1024) void k_stats(
    const float* __restrict__ part, float* __restrict__ scal)
{
    int tid = threadIdx.x;
    float s = 0.f, q = 0.f;
    for (int i = tid; i < 2048; i += 1024) {
        s += part[2 * i];
        q += part[2 * i + 1];
    }
#pragma unroll
    for (int m = 32; m >= 1; m >>= 1) {
        s += __shfl_xor(s, m, 64);
        q += __shfl_xor(q, m, 64);
    }
    __shared__ float sh[32];
    int wid = tid >> 6, lane = tid & 63;
    if (lane == 0) { sh[wid] = s; sh[wid + 16] = q; }
    __syncthreads();
    if (tid == 0) {
        float S = 0.f, Q = 0.f;
#pragma unroll
        for (int i = 0; i < 16; ++i) { S += sh[i]; Q += sh[i + 16]; }
        const float M = (float)(N_NODES * DIM);
        float mean = S / M;
        float var  = (Q - S * S / M) / (M - 1.0f);
        scal[0] = mean;
        scal[1] = 1.0f / sqrtf(var);
    }
}

// ---------------- Kernel 3: per-node routing + remix ----------------------
// One block per node. The 64 KiB vocab slice is streamed ONCE from HBM and
// kept ENTIRELY IN REGISTERS as bf16 (32 VGPRs/thread: thread holds
// e = 4i+wid (i=0..15), v = 4*lane..4*lane+3). No vocab LDS tile at all:
// LDS drops 38->5.3 KiB, __launch_bounds__(256,6) lifts occupancy to
// 6 blocks/CU so the HBM stream stays deep. Pass A fused into the load
// loop; Pass B runs from registers with a 16-value shfl butterfly reduce.
__global__ __launch_bounds__(256, 6) void k_remix(
    const float* __restrict__ vocab, const float* __restrict__ graw,
    const float* __restrict__ scal,
    const float* __restrict__ rclip, const float* __restrict__ rsharp,
    float* __restrict__ out)
{
    __shared__ __align__(16) float dpart[4 * VOC];  // 4 KiB per-wave d partials
    __shared__ __align__(16) float p_s[VOC];        // 1 KiB
    __shared__ float red_s[DIM];                    // 256 B
    __shared__ float sh[8];

    const int tid = threadIdx.x;
    const int n = blockIdx.x;
    const int wid = tid >> 6, lane = tid & 63;

    // per-lane standardized g (lane index == e); one coalesced 256B load
    // per wave, overlaps with the vocab stream. No LDS, no barrier.
    const float mean = scal[0], istd = scal[1];
    const float gme = (graw[(size_t)n * DIM + lane] - mean) * istd;

    const float4* vb4 = (const float4*)(vocab + (size_t)n * (DIM * VOC));

    // ---- fused stream: load fp32, accumulate Pass-A partials, pack bf16 --
    u32 pkx[16], pky[16];
    float d0 = 0.f, d1 = 0.f, d2 = 0.f, d3 = 0.f;
#pragma unroll
    for (int i = 0; i < 16; ++i) {
        float4 w = vb4[i * 256 + tid];      // wave reads 1KiB contiguous
        // e = 4*i + wid; broadcast g[e] from the wave's register copy
        const float ge = __shfl(gme, 4 * i + wid, 64);
        d0 = fmaf(ge, w.x, d0);
        d1 = fmaf(ge, w.y, d1);
        d2 = fmaf(ge, w.z, d2);
        d3 = fmaf(ge, w.w, d3);
        pkx[i] = pk_bf16(w.x, w.y);
        pky[i] = pk_bf16(w.z, w.w);
    }
    // publish per-wave d partials: v = lane*4+j, wave wid covers e≡wid (mod 4)
    float4 dp; dp.x = d0; dp.y = d1; dp.z = d2; dp.w = d3;
    *(float4*)&dpart[wid * VOC + lane * 4] = dp;
    __syncthreads();

    // d for v = tid: sum the 4 wave partials (stride-1KiB, conflict-free)
    float d = dpart[0 * VOC + tid] + dpart[1 * VOC + tid]
            + dpart[2 * VOC + tid] + dpart[3 * VOC + tid];

    // ---- stats of d over 256 lanes (sum, sumsq), ddof=1 ----
    float s = d, q = d * d;
#pragma unroll
    for (int m = 32; m >= 1; m >>= 1) {
        s += __shfl_xor(s, m, 64);
        q += __shfl_xor(q, m, 64);
    }
    if (lane == 0) { sh[wid] = s; sh[wid + 4] = q; }
    __syncthreads();
    float S = sh[0] + sh[1] + sh[2] + sh[3];
    float Q = sh[4] + sh[5] + sh[6] + sh[7];
    float mD  = S * (1.0f / VOC);
    float var = (Q - S * S * (1.0f / VOC)) * (1.0f / (VOC - 1));
    float sdD = sqrtf(fmaxf(var, 0.f));

    float clip = expf(rclip[0]);                       // soft_clip
    float l2s  = rsharp[0] * 1.44269504088896f;        // log2(sharpness)

    float dn = (d - mD) / (sdD + 0.001f);
    float tt = tanhf(dn / clip) * clip;
    float p  = exp2f(tt * l2s);                        // sharpness ** tt
    p_s[tid] = p;

    float ps = p;
#pragma unroll
    for (int m = 32; m >= 1; m >>= 1) ps += __shfl_xor(ps, m, 64);
    __syncthreads();                 // protect sh; publish p_s
    if (lane == 0) sh[wid] = ps;
    __syncthreads();
    float invden = 1.0f / (sh[0] + sh[1] + sh[2] + sh[3] + 0.001f);

    // ---- Pass B: out[e] = invden * sum_v vocab[e][v] * p[v], from regs ---
    // thread holds vocab[4i+wid][4*lane..+3]; needs p[4*lane..+3]
    const float4 pv = *(const float4*)&p_s[lane * 4];
#pragma unroll
    for (int i = 0; i < 16; ++i) {
        float a = fmaf(bflo(pkx[i]), pv.x,
                  fmaf(bfhi(pkx[i]), pv.y,
                  fmaf(bflo(pky[i]), pv.z,
                       bfhi(pky[i]) * pv.w)));
#pragma unroll
        for (int m = 32; m >= 1; m >>= 1) a += __shfl_xor(a, m, 64);
        if (lane == 0) red_s[4 * i + wid] = a;   // e = 4i+wid
    }
    __syncthreads();
    if (tid < DIM) out[(size_t)n * DIM + tid] = red_s[tid] * invden;
}

extern "C" void kernel_launch(void* const* d_in, const int* in_sizes, int n_in,
                              void* d_out, int out_size, void* d_ws, size_t ws_size,
                              hipStream_t stream)
{
    const float* x      = (const float*)d_in[0];
    const float* memes  = (const float*)d_in[1];
    const int*   idx    = (const int*)d_in[2];
    const float* vocab  = (const float*)d_in[3];
    const float* rclip  = (const float*)d_in[4];
    const float* rsharp = (const float*)d_in[5];
    float* out = (float*)d_out;

    float* scal = (float*)d_ws;                    // 2 floats
    float* part = (float*)((char*)d_ws + 64);      // 2048*2 floats (16 KiB)
    float* graw = (float*)((char*)d_ws + 32768);   // 8192*64 floats (2 MiB)

    k_gather<<<N_NODES / 4, 256, 0, stream>>>(x, memes, idx, graw, part);
    k_stats<<<1, 1024, 0, stream>>>(part, scal);
    k_remix<<<N_NODES, 256, 0, stream>>>(vocab, graw, scal, rclip, rsharp, out);
}

// Round 4
// 699.668 us; speedup vs baseline: 1.0122x; 1.0122x over previous
//
#include <hip/hip_runtime.h>
#include <hip/hip_bf16.h>

#define N_NODES 8192
#define DIM 64
#define VIS 2048
#define KIN 32
#define VOC 256

typedef unsigned short u16;
typedef unsigned int u32;
typedef float f32x4 __attribute__((ext_vector_type(4)));

__device__ __forceinline__ float bflo(u32 w) {
    union { u32 i; float f; } c; c.i = w << 16; return c.f;
}
__device__ __forceinline__ float bfhi(u32 w) {
    union { u32 i; float f; } c; c.i = w & 0xffff0000u; return c.f;
}
// pack two fp32 -> two bf16 (RNE), low word = a
__device__ __forceinline__ u32 pk_bf16(float a, float b) {
    __hip_bfloat162 h = __float22bfloat162_rn(make_float2(a, b));
    u32 u; __builtin_memcpy(&u, &h, 4); return u;
}

// ---------------- Kernel 1: gather + mean over K, partial global stats ----
__global__ __launch_bounds__(256) void k_gather(
    const float* __restrict__ x, const float* __restrict__ memes,
    const int* __restrict__ idx, float* __restrict__ graw,
    float* __restrict__ part)
{
    int tid  = threadIdx.x;
    int wid  = tid >> 6;
    int lane = tid & 63;
    int n = blockIdx.x * 4 + wid;           // one wave per node
    const int* irow = idx + n * KIN;

    float acc = 0.f;
#pragma unroll
    for (int k = 0; k < KIN; ++k) {
        int id = irow[k];                   // wave-uniform load
        const float* row = (id < VIS) ? (x + (size_t)id * DIM)
                                      : (memes + (size_t)(id - VIS) * DIM);
        acc += row[lane];                   // 256B contiguous per wave
    }
    float g = acc * (1.0f / KIN);
    graw[(size_t)n * DIM + lane] = g;

    float s = g, q = g * g;
#pragma unroll
    for (int m = 32; m >= 1; m >>= 1) {
        s += __shfl_xor(s, m, 64);
        q += __shfl_xor(q, m, 64);
    }
    __shared__ float sh[8];
    if (lane == 0) { sh[wid] = s; sh[wid + 4] = q; }
    __syncthreads();
    if (tid == 0) {
        part[blockIdx.x * 2 + 0] = sh[0] + sh[1] + sh[2] + sh[3];
        part[blockIdx.x * 2 + 1] = sh[4] + sh[5] + sh[6] + sh[7];
    }
}

// ---------------- Kernel 2: finish global mean / inv-std (ddof=1) ---------
__global__ __launch_bounds__(1024) void k_stats(
    const float* __restrict__ part, float* __restrict__ scal)
{
    int tid = threadIdx.x;
    float s = 0.f, q = 0.f;
    for (int i = tid; i < 2048; i += 1024) {
        s += part[2 * i];
        q += part[2 * i + 1];
    }
#pragma unroll
    for (int m = 32; m >= 1; m >>= 1) {
        s += __shfl_xor(s, m, 64);
        q += __shfl_xor(q, m, 64);
    }
    __shared__ float sh[32];
    int wid = tid >> 6, lane = tid & 63;
    if (lane == 0) { sh[wid] = s; sh[wid + 16] = q; }
    __syncthreads();
    if (tid == 0) {
        float S = 0.f, Q = 0.f;
#pragma unroll
        for (int i = 0; i < 16; ++i) { S += sh[i]; Q += sh[i + 16]; }
        const float M = (float)(N_NODES * DIM);
        float mean = S / M;
        float var  = (Q - S * S / M) / (M - 1.0f);
        scal[0] = mean;
        scal[1] = 1.0f / sqrtf(var);
    }
}

// ---------------- Kernel 3: per-node routing + remix ----------------------
// TWO nodes per block, load streams interleaved: every latency slot of
// stream A is filled by independent loads/FMAs of stream B (2x MLP per
// wave), and the barrier-synchronized tail (stats/p/Pass-B) is amortized
// over 2x the HBM bytes. Vocab kept register-resident as bf16
// (pkA+pkB = 64 VGPRs). Loads are non-temporal (read-once stream).
__global__ __launch_bounds__(256, 4) void k_remix(
    const float* __restrict__ vocab, const float* __restrict__ graw,
    const float* __restrict__ scal,
    const float* __restrict__ rclip, const float* __restrict__ rsharp,
    float* __restrict__ out)
{
    __shared__ __align__(16) float dpartA[4 * VOC];  // 4 KiB
    __shared__ __align__(16) float dpartB[4 * VOC];  // 4 KiB
    __shared__ __align__(16) float p_sA[VOC];
    __shared__ __align__(16) float p_sB[VOC];
    __shared__ float red_A[DIM], red_B[DIM];
    __shared__ float sh[16];
    __shared__ float sh2[8];

    const int tid = threadIdx.x;
    const int wid = tid >> 6, lane = tid & 63;
    const int nA = blockIdx.x * 2;
    const int nB = nA + 1;

    const float mean = scal[0], istd = scal[1];
    const float gA = (graw[(size_t)nA * DIM + lane] - mean) * istd;
    const float gB = (graw[(size_t)nB * DIM + lane] - mean) * istd;

    const f32x4* vbA = (const f32x4*)(vocab + (size_t)nA * (DIM * VOC));
    const f32x4* vbB = (const f32x4*)(vocab + (size_t)nB * (DIM * VOC));

    // ---- fused interleaved stream: load, Pass-A partials, pack bf16 ------
    u32 pkAx[16], pkAy[16], pkBx[16], pkBy[16];
    float dA0 = 0.f, dA1 = 0.f, dA2 = 0.f, dA3 = 0.f;
    float dB0 = 0.f, dB1 = 0.f, dB2 = 0.f, dB3 = 0.f;
#pragma unroll
    for (int i = 0; i < 16; ++i) {
        f32x4 wa = __builtin_nontemporal_load(vbA + i * 256 + tid);
        f32x4 wb = __builtin_nontemporal_load(vbB + i * 256 + tid);
        const float geA = __shfl(gA, 4 * i + wid, 64);   // e = 4i+wid
        const float geB = __shfl(gB, 4 * i + wid, 64);
        dA0 = fmaf(geA, wa.x, dA0);
        dA1 = fmaf(geA, wa.y, dA1);
        dA2 = fmaf(geA, wa.z, dA2);
        dA3 = fmaf(geA, wa.w, dA3);
        pkAx[i] = pk_bf16(wa.x, wa.y);
        pkAy[i] = pk_bf16(wa.z, wa.w);
        dB0 = fmaf(geB, wb.x, dB0);
        dB1 = fmaf(geB, wb.y, dB1);
        dB2 = fmaf(geB, wb.z, dB2);
        dB3 = fmaf(geB, wb.w, dB3);
        pkBx[i] = pk_bf16(wb.x, wb.y);
        pkBy[i] = pk_bf16(wb.z, wb.w);
    }
    {   // publish per-wave d partials: v = lane*4+j, wave wid has e≡wid (mod 4)
        float4 dp;
        dp.x = dA0; dp.y = dA1; dp.z = dA2; dp.w = dA3;
        *(float4*)&dpartA[wid * VOC + lane * 4] = dp;
        dp.x = dB0; dp.y = dB1; dp.z = dB2; dp.w = dB3;
        *(float4*)&dpartB[wid * VOC + lane * 4] = dp;
    }
    __syncthreads();

    // d for v = tid (both nodes)
    float dA = dpartA[0 * VOC + tid] + dpartA[1 * VOC + tid]
             + dpartA[2 * VOC + tid] + dpartA[3 * VOC + tid];
    float dB = dpartB[0 * VOC + tid] + dpartB[1 * VOC + tid]
             + dpartB[2 * VOC + tid] + dpartB[3 * VOC + tid];

    // ---- stats over 256 v-lanes (sum, sumsq), ddof=1, both nodes --------
    float sA = dA, qA = dA * dA, sB = dB, qB = dB * dB;
#pragma unroll
    for (int m = 32; m >= 1; m >>= 1) {
        sA += __shfl_xor(sA, m, 64);
        qA += __shfl_xor(qA, m, 64);
        sB += __shfl_xor(sB, m, 64);
        qB += __shfl_xor(qB, m, 64);
    }
    if (lane == 0) {
        sh[wid] = sA; sh[wid + 4] = qA;
        sh[wid + 8] = sB; sh[wid + 12] = qB;
    }
    __syncthreads();
    float SA = sh[0] + sh[1] + sh[2] + sh[3];
    float QA = sh[4] + sh[5] + sh[6] + sh[7];
    float SB = sh[8] + sh[9] + sh[10] + sh[11];
    float QB = sh[12] + sh[13] + sh[14] + sh[15];

    const float clip = expf(rclip[0]);
    const float l2s  = rsharp[0] * 1.44269504088896f;  // log2(sharpness)

    float mDA  = SA * (1.0f / VOC);
    float varA = (QA - SA * SA * (1.0f / VOC)) * (1.0f / (VOC - 1));
    float dnA  = (dA - mDA) / (sqrtf(fmaxf(varA, 0.f)) + 0.001f);
    float pA   = exp2f(tanhf(dnA / clip) * clip * l2s);
    float mDB  = SB * (1.0f / VOC);
    float varB = (QB - SB * SB * (1.0f / VOC)) * (1.0f / (VOC - 1));
    float dnB  = (dB - mDB) / (sqrtf(fmaxf(varB, 0.f)) + 0.001f);
    float pB   = exp2f(tanhf(dnB / clip) * clip * l2s);

    p_sA[tid] = pA;
    p_sB[tid] = pB;
    float psA = pA, psB = pB;
#pragma unroll
    for (int m = 32; m >= 1; m >>= 1) {
        psA += __shfl_xor(psA, m, 64);
        psB += __shfl_xor(psB, m, 64);
    }
    if (lane == 0) { sh2[wid] = psA; sh2[wid + 4] = psB; }
    __syncthreads();
    const float invdenA = 1.0f / (sh2[0] + sh2[1] + sh2[2] + sh2[3] + 0.001f);
    const float invdenB = 1.0f / (sh2[4] + sh2[5] + sh2[6] + sh2[7] + 0.001f);

    // ---- Pass B: out[e] = invden * sum_v vocab[e][v] * p[v], from regs ---
    const float4 pvA = *(const float4*)&p_sA[lane * 4];
    const float4 pvB = *(const float4*)&p_sB[lane * 4];
#pragma unroll
    for (int i = 0; i < 16; ++i) {
        float aA = fmaf(bflo(pkAx[i]), pvA.x,
                   fmaf(bfhi(pkAx[i]), pvA.y,
                   fmaf(bflo(pkAy[i]), pvA.z,
                        bfhi(pkAy[i]) * pvA.w)));
        float aB = fmaf(bflo(pkBx[i]), pvB.x,
                   fmaf(bfhi(pkBx[i]), pvB.y,
                   fmaf(bflo(pkBy[i]), pvB.z,
                        bfhi(pkBy[i]) * pvB.w)));
#pragma unroll
        for (int m = 32; m >= 1; m >>= 1) {
            aA += __shfl_xor(aA, m, 64);
            aB += __shfl_xor(aB, m, 64);
        }
        if (lane == 0) { red_A[4 * i + wid] = aA; red_B[4 * i + wid] = aB; }
    }
    __syncthreads();
    if (tid < DIM) {
        out[(size_t)nA * DIM + tid] = red_A[tid] * invdenA;
    } else if (tid < 2 * DIM) {
        out[(size_t)nB * DIM + (tid - DIM)] = red_B[tid - DIM] * invdenB;
    }
}

extern "C" void kernel_launch(void* const* d_in, const int* in_sizes, int n_in,
                              void* d_out, int out_size, void* d_ws, size_t ws_size,
                              hipStream_t stream)
{
    const float* x      = (const float*)d_in[0];
    const float* memes  = (const float*)d_in[1];
    const int*   idx    = (const int*)d_in[2];
    const float* vocab  = (const float*)d_in[3];
    const float* rclip  = (const float*)d_in[4];
    const float* rsharp = (const float*)d_in[5];
    float* out = (float*)d_out;

    float* scal = (float*)d_ws;                    // 2 floats
    float* part = (float*)((char*)d_ws + 64);      // 2048*2 floats (16 KiB)
    float* graw = (float*)((char*)d_ws + 32768);   // 8192*64 floats (2 MiB)

    k_gather<<<N_NODES / 4, 256, 0, stream>>>(x, memes, idx, graw, part);
    k_stats<<<1, 1024, 0, stream>>>(part, scal);
    k_remix<<<N_NODES / 2, 256, 0, stream>>>(vocab, graw, scal, rclip, rsharp, out);
}